// Round 1
// baseline (1688.207 us; speedup 1.0000x reference)
//
#include <hip/hip_runtime.h>
#include <math.h>

#define BB 2
#define CCH 128
#define LL 4096
#define HEADS 4
#define DH 32
#define NGROUPS 16
#define CPG 8
#define EPSV 1e-5f
#define TM 64

// ---------------- GroupNorm ----------------
__global__ __launch_bounds__(256) void gn_kernel(const float* __restrict__ x,
                                                 const float* __restrict__ gw,
                                                 const float* __restrict__ gb,
                                                 float* __restrict__ xn) {
    int bg = blockIdx.x;
    int b = bg >> 4, g = bg & 15;
    const float* xp = x + ((size_t)(b * CCH + g * CPG)) * LL;
    float* xnp = xn + ((size_t)(b * CCH + g * CPG)) * LL;
    const int n = CPG * LL;  // 32768, contiguous
    float s = 0.f, s2 = 0.f;
    for (int i = threadIdx.x * 4; i < n; i += blockDim.x * 4) {
        float4 v = *(const float4*)(xp + i);
        s += v.x + v.y + v.z + v.w;
        s2 += v.x * v.x + v.y * v.y + v.z * v.z + v.w * v.w;
    }
    for (int off = 32; off; off >>= 1) {
        s += __shfl_down(s, off);
        s2 += __shfl_down(s2, off);
    }
    __shared__ float rs[4], rs2[4];
    __shared__ float smean, srstd;
    int wave = threadIdx.x >> 6, lane = threadIdx.x & 63;
    if (lane == 0) { rs[wave] = s; rs2[wave] = s2; }
    __syncthreads();
    if (threadIdx.x == 0) {
        float ts = rs[0] + rs[1] + rs[2] + rs[3];
        float ts2 = rs2[0] + rs2[1] + rs2[2] + rs2[3];
        float mean = ts / n;
        float var = ts2 / n - mean * mean;
        smean = mean;
        srstd = rsqrtf(var + EPSV);
    }
    __syncthreads();
    float mean = smean, rstd = srstd;
    for (int i = threadIdx.x * 4; i < n; i += blockDim.x * 4) {
        int c = g * CPG + (i >> 12);  // i / LL (same for all 4 lanes of the float4)
        float w = gw[c], bv = gb[c];
        float4 v = *(const float4*)(xp + i);
        float4 r;
        r.x = (v.x - mean) * rstd * w + bv;
        r.y = (v.y - mean) * rstd * w + bv;
        r.z = (v.z - mean) * rstd * w + bv;
        r.w = (v.w - mean) * rstd * w + bv;
        *(float4*)(xnp + i) = r;
    }
}

// ---------------- QKV projection: qkv[b,o,l] = sum_c w[o,c]*xn[b,c,l] ----------------
__global__ __launch_bounds__(256) void qkv_kernel(const float* __restrict__ xn,
                                                  const float* __restrict__ w,
                                                  float* __restrict__ qkv) {
    int l = blockIdx.x * 256 + threadIdx.x;
    int o = blockIdx.y;
    int b = blockIdx.z;
    const float* wrow = w + o * CCH;
    const float* xnb = xn + (size_t)b * CCH * LL + l;
    float acc = 0.f;
#pragma unroll 8
    for (int c = 0; c < CCH; ++c) acc += wrow[c] * xnb[(size_t)c * LL];
    qkv[((size_t)b * 3 * CCH + o) * LL + l] = acc;
}

// ---------------- Flash attention: one q-row per thread ----------------
__global__ __launch_bounds__(64) void attn_kernel(const float* __restrict__ qkv,
                                                  float* __restrict__ ocat) {
    __shared__ float Ks[TM][DH + 4];  // stride 36 floats: 16B-aligned rows, spread write banks
    __shared__ float Vs[TM][DH + 4];
    int b = blockIdx.z, h = blockIdx.y;
    int qrow = blockIdx.x * 64 + threadIdx.x;
    const float* qbase = qkv + (size_t)b * 3 * CCH * LL;
    const float scale = 0.17677669529663687f;  // 1/sqrt(32)
    float q[DH], o[DH];
#pragma unroll
    for (int d = 0; d < DH; ++d) {
        q[d] = qbase[(size_t)(h * DH + d) * LL + qrow] * scale;
        o[d] = 0.f;
    }
    float mmax = -1e30f, lsum = 0.f;
    for (int m0 = 0; m0 < LL; m0 += TM) {
        // stage K/V tile: coalesced in m (contiguous), layout [m][d]
        for (int idx = threadIdx.x; idx < TM * DH; idx += 64) {
            int d = idx >> 6, ml = idx & 63;
            Ks[ml][d] = qbase[(size_t)(CCH + h * DH + d) * LL + m0 + ml];
            Vs[ml][d] = qbase[(size_t)(2 * CCH + h * DH + d) * LL + m0 + ml];
        }
        __syncthreads();
        for (int c0 = 0; c0 < TM; c0 += 32) {
            float sc[32];
            float tmax = mmax;
#pragma unroll
            for (int m = 0; m < 32; ++m) {
                float s = 0.f;
#pragma unroll
                for (int d = 0; d < DH; d += 4) {
                    float4 kv = *(const float4*)&Ks[c0 + m][d];
                    s += q[d] * kv.x + q[d + 1] * kv.y + q[d + 2] * kv.z + q[d + 3] * kv.w;
                }
                sc[m] = s;
                tmax = fmaxf(tmax, s);
            }
            float corr = __expf(mmax - tmax);
            lsum *= corr;
#pragma unroll
            for (int d = 0; d < DH; ++d) o[d] *= corr;
#pragma unroll
            for (int m = 0; m < 32; ++m) {
                float p = __expf(sc[m] - tmax);
                lsum += p;
#pragma unroll
                for (int d = 0; d < DH; d += 4) {
                    float4 vv = *(const float4*)&Vs[c0 + m][d];
                    o[d] += p * vv.x;
                    o[d + 1] += p * vv.y;
                    o[d + 2] += p * vv.z;
                    o[d + 3] += p * vv.w;
                }
            }
            mmax = tmax;
        }
        __syncthreads();
    }
    float inv = 1.f / lsum;
#pragma unroll
    for (int d = 0; d < DH; ++d)
        ocat[((size_t)b * CCH + h * DH + d) * LL + qrow] = o[d] * inv;
}

// ---------------- Out projection + bias + residual ----------------
__global__ __launch_bounds__(256) void out_kernel(const float* __restrict__ ocat,
                                                  const float* __restrict__ w,
                                                  const float* __restrict__ bo,
                                                  const float* __restrict__ x,
                                                  float* __restrict__ out) {
    int l = blockIdx.x * 256 + threadIdx.x;
    int oc = blockIdx.y;
    int b = blockIdx.z;
    const float* wrow = w + oc * CCH;
    const float* ob = ocat + (size_t)b * CCH * LL + l;
    float acc = bo[oc];
#pragma unroll 8
    for (int c = 0; c < CCH; ++c) acc += wrow[c] * ob[(size_t)c * LL];
    size_t oi = ((size_t)b * CCH + oc) * LL + l;
    out[oi] = x[oi] + acc;
}

extern "C" void kernel_launch(void* const* d_in, const int* in_sizes, int n_in,
                              void* d_out, int out_size, void* d_ws, size_t ws_size,
                              hipStream_t stream) {
    const float* x = (const float*)d_in[0];
    const float* gn_w = (const float*)d_in[1];
    const float* gn_b = (const float*)d_in[2];
    const float* w_qkv = (const float*)d_in[3];
    const float* w_out = (const float*)d_in[4];
    const float* b_out = (const float*)d_in[5];
    float* out = (float*)d_out;

    float* xn = (float*)d_ws;                      // B*C*L floats = 4 MB
    float* qkv = xn + (size_t)BB * CCH * LL;       // B*3C*L floats = 12 MB
    float* ocat = qkv + (size_t)BB * 3 * CCH * LL; // B*C*L floats = 4 MB

    gn_kernel<<<dim3(BB * NGROUPS), dim3(256), 0, stream>>>(x, gn_w, gn_b, xn);
    qkv_kernel<<<dim3(LL / 256, 3 * CCH, BB), dim3(256), 0, stream>>>(xn, w_qkv, qkv);
    attn_kernel<<<dim3(LL / TM, HEADS, BB), dim3(64), 0, stream>>>(qkv, ocat);
    out_kernel<<<dim3(LL / 256, CCH, BB), dim3(256), 0, stream>>>(ocat, w_out, b_out, x, out);
}

// Round 2
// 188.580 us; speedup vs baseline: 8.9522x; 8.9522x over previous
//
#include <hip/hip_runtime.h>
#include <hip/hip_bf16.h>
#include <math.h>

#define BB 2
#define CCH 128
#define LL 4096
#define HEADS 4
#define DH 32
#define NGROUPS 16
#define CPG 8
#define EPSV 1e-5f

typedef float f32x4 __attribute__((ext_vector_type(4)));
typedef short bf16x8 __attribute__((ext_vector_type(8)));

__device__ inline unsigned short f2bf(float x) {
    union { float f; unsigned u; } v; v.f = x;
    unsigned r = v.u + 0x7fffu + ((v.u >> 16) & 1u);
    return (unsigned short)(r >> 16);
}

// ---------------- GroupNorm ----------------
__global__ __launch_bounds__(256) void gn_kernel(const float* __restrict__ x,
                                                 const float* __restrict__ gw,
                                                 const float* __restrict__ gb,
                                                 float* __restrict__ xn) {
    int bg = blockIdx.x;
    int b = bg >> 4, g = bg & 15;
    const float* xp = x + ((size_t)(b * CCH + g * CPG)) * LL;
    float* xnp = xn + ((size_t)(b * CCH + g * CPG)) * LL;
    const int n = CPG * LL;  // 32768, contiguous
    float s = 0.f, s2 = 0.f;
    for (int i = threadIdx.x * 4; i < n; i += blockDim.x * 4) {
        float4 v = *(const float4*)(xp + i);
        s += v.x + v.y + v.z + v.w;
        s2 += v.x * v.x + v.y * v.y + v.z * v.z + v.w * v.w;
    }
    for (int off = 32; off; off >>= 1) {
        s += __shfl_down(s, off);
        s2 += __shfl_down(s2, off);
    }
    __shared__ float rs[4], rs2[4];
    __shared__ float smean, srstd;
    int wave = threadIdx.x >> 6, lane = threadIdx.x & 63;
    if (lane == 0) { rs[wave] = s; rs2[wave] = s2; }
    __syncthreads();
    if (threadIdx.x == 0) {
        float ts = rs[0] + rs[1] + rs[2] + rs[3];
        float ts2 = rs2[0] + rs2[1] + rs2[2] + rs2[3];
        float mean = ts / n;
        float var = ts2 / n - mean * mean;
        smean = mean;
        srstd = rsqrtf(var + EPSV);
    }
    __syncthreads();
    float mean = smean, rstd = srstd;
    for (int i = threadIdx.x * 4; i < n; i += blockDim.x * 4) {
        int c = g * CPG + (i >> 12);
        float w = gw[c], bv = gb[c];
        float4 v = *(const float4*)(xp + i);
        float4 r;
        r.x = (v.x - mean) * rstd * w + bv;
        r.y = (v.y - mean) * rstd * w + bv;
        r.z = (v.z - mean) * rstd * w + bv;
        r.w = (v.w - mean) * rstd * w + bv;
        *(float4*)(xnp + i) = r;
    }
}

// ---------------- QKV projection ----------------
__global__ __launch_bounds__(256) void qkv_kernel(const float* __restrict__ xn,
                                                  const float* __restrict__ w,
                                                  float* __restrict__ qkv) {
    int l = blockIdx.x * 256 + threadIdx.x;
    int o = blockIdx.y;
    int b = blockIdx.z;
    const float* wrow = w + o * CCH;
    const float* xnb = xn + (size_t)b * CCH * LL + l;
    float acc = 0.f;
#pragma unroll 8
    for (int c = 0; c < CCH; ++c) acc += wrow[c] * xnb[(size_t)c * LL];
    qkv[((size_t)b * 3 * CCH + o) * LL + l] = acc;
}

// ---------------- K: transpose + cvt to bf16, Kb[bh][kv][d] ----------------
__global__ __launch_bounds__(256) void cvtk_kernel(const float* __restrict__ qkv,
                                                   unsigned short* __restrict__ Kb) {
    int tt = blockIdx.x * 256 + threadIdx.x;  // token over bh*L (32768)
    int bh = tt >> 12, kv = tt & 4095;
    int b = bh >> 2, h = bh & 3;
    const float* src = qkv + ((size_t)(b * 3 * CCH) + CCH + h * DH) * LL + kv;
    unsigned int wbuf[16];
#pragma unroll
    for (int dp = 0; dp < 16; ++dp) {
        unsigned lo = f2bf(src[(size_t)(2 * dp) * LL]);
        unsigned hi = f2bf(src[(size_t)(2 * dp + 1) * LL]);
        wbuf[dp] = lo | (hi << 16);
    }
    unsigned int* dst = (unsigned int*)(Kb + ((size_t)bh * LL + kv) * DH);
#pragma unroll
    for (int i = 0; i < 4; ++i)
        *(uint4*)(dst + i * 4) = make_uint4(wbuf[4 * i], wbuf[4 * i + 1], wbuf[4 * i + 2], wbuf[4 * i + 3]);
}

// ---------------- V: straight cvt to bf16, Vb[bh][d][kv] (same layout as qkv V slab) ----------------
__global__ __launch_bounds__(256) void cvtv_kernel(const float* __restrict__ qkv,
                                                   unsigned short* __restrict__ Vb) {
    size_t id = (size_t)(blockIdx.x * 256 + threadIdx.x) * 8;  // over B*C*L = 1048576
    int b = (int)(id >> 19);
    size_t rem = id & 524287;
    const float* src = qkv + (size_t)b * 3 * CCH * LL + (size_t)2 * CCH * LL + rem;
    float4 v0 = *(const float4*)src;
    float4 v1 = *(const float4*)(src + 4);
    unsigned int w0 = f2bf(v0.x) | ((unsigned)f2bf(v0.y) << 16);
    unsigned int w1 = f2bf(v0.z) | ((unsigned)f2bf(v0.w) << 16);
    unsigned int w2 = f2bf(v1.x) | ((unsigned)f2bf(v1.y) << 16);
    unsigned int w3 = f2bf(v1.z) | ((unsigned)f2bf(v1.w) << 16);
    *(uint4*)(Vb + (size_t)b * CCH * LL + rem) = make_uint4(w0, w1, w2, w3);
}

// ---------------- MFMA flash attention ----------------
// Swapped form: S^T[kv][q] = mfma(A=K[16kv x 32d], B=Q^T[32d x 16q])
//               O^T[d][q] += mfma(A=V^T[16d x 32kv], B=P^T[32kv x 16q])
__global__ __launch_bounds__(256) void attn_kernel(const float* __restrict__ qkv,
                                                   const unsigned short* __restrict__ Kb,
                                                   const unsigned short* __restrict__ Vb,
                                                   float* __restrict__ ocat) {
    __shared__ __align__(16) short Pl[4][16][72];  // per-wave P^T staging, pad->2-way conflicts only
    int b = blockIdx.z, h = blockIdx.y, bh = b * HEADS + h;
    int wid = threadIdx.x >> 6, lane = threadIdx.x & 63;
    int lm = lane & 15, lg = lane >> 4;
    int q0 = blockIdx.x * 64 + wid * 16;

    // Q fragment (once): q = q0+lm, d = 8*lg+j, from f32 qkv (coalesced per 16-lane group)
    const float* qsrc = qkv + ((size_t)b * 3 * CCH + h * DH + 8 * lg) * LL + q0 + lm;
    bf16x8 qf;
#pragma unroll
    for (int j = 0; j < 8; ++j) qf[j] = (short)f2bf(qsrc[(size_t)j * LL]);

    const unsigned short* Kbh = Kb + (size_t)bh * LL * DH;
    const unsigned short* Vbh = Vb + (size_t)bh * DH * LL;

    f32x4 accO[2] = {{0.f, 0.f, 0.f, 0.f}, {0.f, 0.f, 0.f, 0.f}};
    float m = -1e30f, lsum = 0.f;
    const float scale = 0.17677669529663687f;  // 1/sqrt(32)

    bf16x8 kf[4];
#pragma unroll
    for (int kc = 0; kc < 4; ++kc)
        kf[kc] = *(const bf16x8*)(Kbh + ((size_t)(kc * 16 + lm)) * DH + 8 * lg);

    for (int m0 = 0; m0 < LL; m0 += 64) {
        // prefetch next K tile's fragments (wraps on last iter; discarded)
        int mn = (m0 + 64) & (LL - 1);
        bf16x8 kn[4];
#pragma unroll
        for (int kc = 0; kc < 4; ++kc)
            kn[kc] = *(const bf16x8*)(Kbh + ((size_t)(mn + kc * 16 + lm)) * DH + 8 * lg);

        // QK^T (swapped): s tile kc holds kv rows kc*16 + 4*lg + r, col q = lm
        f32x4 s[4];
#pragma unroll
        for (int kc = 0; kc < 4; ++kc)
            s[kc] = __builtin_amdgcn_mfma_f32_16x16x32_bf16(kf[kc], qf, (f32x4){0.f, 0.f, 0.f, 0.f}, 0, 0, 0);

        // issue V fragment loads early: latency hides under softmax VALU
        bf16x8 vf[2][2];
#pragma unroll
        for (int ch = 0; ch < 2; ++ch)
#pragma unroll
            for (int dt = 0; dt < 2; ++dt)
                vf[ch][dt] = *(const bf16x8*)(Vbh + ((size_t)(dt * 16 + lm)) * LL + m0 + ch * 32 + 8 * lg);

        // online softmax over this 64-kv tile
        float tmax = -1e30f;
#pragma unroll
        for (int kc = 0; kc < 4; ++kc)
#pragma unroll
            for (int r = 0; r < 4; ++r) {
                s[kc][r] *= scale;
                tmax = fmaxf(tmax, s[kc][r]);
            }
        tmax = fmaxf(tmax, __shfl_xor(tmax, 16));
        tmax = fmaxf(tmax, __shfl_xor(tmax, 32));
        float mnew = fmaxf(m, tmax);
        float corr = __expf(m - mnew);
        float tsum = 0.f;
        unsigned pw[4][2];
#pragma unroll
        for (int kc = 0; kc < 4; ++kc) {
            float p0 = __expf(s[kc][0] - mnew), p1 = __expf(s[kc][1] - mnew);
            float p2 = __expf(s[kc][2] - mnew), p3 = __expf(s[kc][3] - mnew);
            tsum += (p0 + p1) + (p2 + p3);
            pw[kc][0] = (unsigned)f2bf(p0) | ((unsigned)f2bf(p1) << 16);
            pw[kc][1] = (unsigned)f2bf(p2) | ((unsigned)f2bf(p3) << 16);
        }
        tsum += __shfl_xor(tsum, 16);
        tsum += __shfl_xor(tsum, 32);
        lsum = lsum * corr + tsum;
        m = mnew;
#pragma unroll
        for (int dt = 0; dt < 2; ++dt)
#pragma unroll
            for (int r = 0; r < 4; ++r) accO[dt][r] *= corr;

        // P^T -> wave-private LDS (write kv-contiguous per q row), read back as B-fragments
#pragma unroll
        for (int kc = 0; kc < 4; ++kc) {
            uint2 u;
            u.x = pw[kc][0];
            u.y = pw[kc][1];
            *(uint2*)&Pl[wid][lm][kc * 16 + 4 * lg] = u;
        }
        bf16x8 pf[2];
#pragma unroll
        for (int ch = 0; ch < 2; ++ch)
            pf[ch] = *(const bf16x8*)&Pl[wid][lm][ch * 32 + 8 * lg];

        // PV: O^T[d][q] accumulate
#pragma unroll
        for (int ch = 0; ch < 2; ++ch)
#pragma unroll
            for (int dt = 0; dt < 2; ++dt)
                accO[dt] = __builtin_amdgcn_mfma_f32_16x16x32_bf16(vf[ch][dt], pf[ch], accO[dt], 0, 0, 0);

#pragma unroll
        for (int kc = 0; kc < 4; ++kc) kf[kc] = kn[kc];
    }

    float inv = 1.f / lsum;
    float* od = ocat + ((size_t)b * CCH + h * DH) * LL + q0 + lm;
#pragma unroll
    for (int dt = 0; dt < 2; ++dt)
#pragma unroll
        for (int r = 0; r < 4; ++r) {
            int d = dt * 16 + 4 * lg + r;
            od[(size_t)d * LL] = accO[dt][r] * inv;
        }
}

// ---------------- Out projection + bias + residual ----------------
__global__ __launch_bounds__(256) void out_kernel(const float* __restrict__ ocat,
                                                  const float* __restrict__ w,
                                                  const float* __restrict__ bo,
                                                  const float* __restrict__ x,
                                                  float* __restrict__ out) {
    int l = blockIdx.x * 256 + threadIdx.x;
    int oc = blockIdx.y;
    int b = blockIdx.z;
    const float* wrow = w + oc * CCH;
    const float* ob = ocat + (size_t)b * CCH * LL + l;
    float acc = bo[oc];
#pragma unroll 8
    for (int c = 0; c < CCH; ++c) acc += wrow[c] * ob[(size_t)c * LL];
    size_t oi = ((size_t)b * CCH + oc) * LL + l;
    out[oi] = x[oi] + acc;
}

extern "C" void kernel_launch(void* const* d_in, const int* in_sizes, int n_in,
                              void* d_out, int out_size, void* d_ws, size_t ws_size,
                              hipStream_t stream) {
    const float* x = (const float*)d_in[0];
    const float* gn_w = (const float*)d_in[1];
    const float* gn_b = (const float*)d_in[2];
    const float* w_qkv = (const float*)d_in[3];
    const float* w_out = (const float*)d_in[4];
    const float* b_out = (const float*)d_in[5];
    float* out = (float*)d_out;

    float* wsf = (float*)d_ws;
    float* xn = wsf;                                   // [0,4MB)  — dead after qkv_kernel
    float* qkv = wsf + (size_t)BB * CCH * LL;          // [4,16MB)
    float* ocat = qkv + (size_t)BB * 3 * CCH * LL;     // [16,20MB)
    unsigned short* Kb = (unsigned short*)d_ws;        // [0,2MB)  — reuses xn region
    unsigned short* Vb = Kb + (size_t)BB * HEADS * LL * DH;  // [2,4MB)

    gn_kernel<<<dim3(BB * NGROUPS), dim3(256), 0, stream>>>(x, gn_w, gn_b, xn);
    qkv_kernel<<<dim3(LL / 256, 3 * CCH, BB), dim3(256), 0, stream>>>(xn, w_qkv, qkv);
    cvtk_kernel<<<dim3(BB * HEADS * LL / 256), dim3(256), 0, stream>>>(qkv, Kb);
    cvtv_kernel<<<dim3(BB * CCH * LL / 8 / 256), dim3(256), 0, stream>>>(qkv, Vb);
    attn_kernel<<<dim3(LL / 64, HEADS, BB), dim3(256), 0, stream>>>(qkv, Kb, Vb, ocat);
    out_kernel<<<dim3(LL / 256, CCH, BB), dim3(256), 0, stream>>>(ocat, w_out, b_out, x, out);
}

// Round 3
// 162.450 us; speedup vs baseline: 10.3922x; 1.1608x over previous
//
#include <hip/hip_runtime.h>
#include <math.h>

#define BB 2
#define CCH 128
#define LL 4096
#define HEADS 4
#define DH 32
#define EPSV 1e-5f

typedef float f32x4 __attribute__((ext_vector_type(4)));
typedef short bf16x8 __attribute__((ext_vector_type(8)));

__device__ inline unsigned short f2bf(float x) {
    union { float f; unsigned u; } v; v.f = x;
    unsigned r = v.u + 0x7fffu + ((v.u >> 16) & 1u);
    return (unsigned short)(r >> 16);
}
__device__ inline float bfbits2f(unsigned bits_hi16) {
    union { unsigned u; float f; } v; v.u = bits_hi16; return v.f;
}
__device__ inline unsigned cvtpk(float lo, float hi) {
    unsigned r;
    asm("v_cvt_pk_bf16_f32 %0, %1, %2" : "=v"(r) : "v"(lo), "v"(hi));
    return r;
}

// ---------------- GN pass 1: partial sums (one block per channel) ----------------
__global__ __launch_bounds__(256) void gn_part(const float* __restrict__ x,
                                               float* __restrict__ ps, float* __restrict__ ps2) {
    const float* xp = x + (size_t)blockIdx.x * 4096;
    float s = 0.f, s2 = 0.f;
#pragma unroll
    for (int it = 0; it < 4; ++it) {
        float4 v = *(const float4*)(xp + it * 1024 + threadIdx.x * 4);
        s += v.x + v.y + v.z + v.w;
        s2 += v.x * v.x + v.y * v.y + v.z * v.z + v.w * v.w;
    }
    for (int off = 32; off; off >>= 1) {
        s += __shfl_down(s, off);
        s2 += __shfl_down(s2, off);
    }
    __shared__ float rs[4], rs2[4];
    int wave = threadIdx.x >> 6, lane = threadIdx.x & 63;
    if (lane == 0) { rs[wave] = s; rs2[wave] = s2; }
    __syncthreads();
    if (threadIdx.x == 0) {
        ps[blockIdx.x] = rs[0] + rs[1] + rs[2] + rs[3];
        ps2[blockIdx.x] = rs2[0] + rs2[1] + rs2[2] + rs2[3];
    }
}

// ---------------- GN pass 2: finalize stats ----------------
__global__ void gn_final(const float* __restrict__ ps, const float* __restrict__ ps2,
                         float* __restrict__ sm, float* __restrict__ sr) {
    int t = threadIdx.x;
    if (t >= 32) return;
    float s = 0.f, s2 = 0.f;
#pragma unroll
    for (int i = 0; i < 8; ++i) { s += ps[t * 8 + i]; s2 += ps2[t * 8 + i]; }
    float mean = s / 32768.f;
    float var = s2 / 32768.f - mean * mean;
    sm[t] = mean;
    sr[t] = rsqrtf(var + EPSV);
}

// ---------------- W prep: hi/lo bf16 split; Q rows pre-scaled by log2e/sqrt(dh) ----------------
__global__ __launch_bounds__(256) void prep_w(const float* __restrict__ w_qkv,
                                              const float* __restrict__ w_out,
                                              unsigned short* __restrict__ Wqh, unsigned short* __restrict__ Wql,
                                              unsigned short* __restrict__ Woh, unsigned short* __restrict__ Wol) {
    int i = blockIdx.x * 256 + threadIdx.x;
    const float qscale = 0.2550350f;  // log2(e)/sqrt(32)
    if (i < 49152) {
        float v = w_qkv[i];
        if (i < 16384) v *= qscale;  // Q rows (o<128)
        unsigned short h = f2bf(v);
        Wqh[i] = h;
        Wql[i] = f2bf(v - bfbits2f((unsigned)h << 16));
    } else {
        int j = i - 49152;
        float v = w_out[j];
        unsigned short h = f2bf(v);
        Woh[j] = h;
        Wol[j] = f2bf(v - bfbits2f((unsigned)h << 16));
    }
}

// ---------------- GN apply + transpose: x[b][c][l] -> xth/xtl[b][l][c] bf16 ----------------
__global__ __launch_bounds__(256) void gn_apply_t(const float* __restrict__ x,
                                                  const float* __restrict__ gw, const float* __restrict__ gb,
                                                  const float* __restrict__ sm, const float* __restrict__ sr,
                                                  unsigned short* __restrict__ xth, unsigned short* __restrict__ xtl) {
    int lt = blockIdx.x, ct = blockIdx.y, b = blockIdx.z;
    int c0 = ct * 32, l0 = lt * 256;
    __shared__ float wsh[32], bsh[32], msh[4], rsh[4];
    __shared__ unsigned short sh[32][264], sl[32][264];
    if (threadIdx.x < 32) { wsh[threadIdx.x] = gw[c0 + threadIdx.x]; bsh[threadIdx.x] = gb[c0 + threadIdx.x]; }
    if (threadIdx.x < 4) {
        int g = (c0 >> 3) + threadIdx.x;
        msh[threadIdx.x] = sm[b * 16 + g];
        rsh[threadIdx.x] = sr[b * 16 + g];
    }
    __syncthreads();
#pragma unroll
    for (int it = 0; it < 8; ++it) {
        int idx = it * 256 + threadIdx.x;  // over 2048 float4
        int cc = idx >> 6, l4 = idx & 63;
        float4 v = *(const float4*)(x + ((size_t)(b * CCH + c0 + cc)) * LL + l0 + l4 * 4);
        float mn = msh[cc >> 3], rstd = rsh[cc >> 3], w = wsh[cc], bv = bsh[cc];
        float a0 = (v.x - mn) * rstd * w + bv;
        float a1 = (v.y - mn) * rstd * w + bv;
        float a2 = (v.z - mn) * rstd * w + bv;
        float a3 = (v.w - mn) * rstd * w + bv;
        unsigned uh01 = cvtpk(a0, a1), uh23 = cvtpk(a2, a3);
        float r0 = a0 - bfbits2f(uh01 << 16), r1 = a1 - bfbits2f(uh01 & 0xffff0000u);
        float r2 = a2 - bfbits2f(uh23 << 16), r3 = a3 - bfbits2f(uh23 & 0xffff0000u);
        unsigned ul01 = cvtpk(r0, r1), ul23 = cvtpk(r2, r3);
        *(uint2*)&sh[cc][l4 * 4] = make_uint2(uh01, uh23);
        *(uint2*)&sl[cc][l4 * 4] = make_uint2(ul01, ul23);
    }
    __syncthreads();
    int t = threadIdx.x;  // row l = l0 + t
    unsigned hw[16], lw[16];
#pragma unroll
    for (int dp = 0; dp < 16; ++dp) {
        hw[dp] = (unsigned)sh[2 * dp][t] | ((unsigned)sh[2 * dp + 1][t] << 16);
        lw[dp] = (unsigned)sl[2 * dp][t] | ((unsigned)sl[2 * dp + 1][t] << 16);
    }
    uint4* dh = (uint4*)(xth + ((size_t)b * LL + l0 + t) * CCH + c0);
    uint4* dl = (uint4*)(xtl + ((size_t)b * LL + l0 + t) * CCH + c0);
#pragma unroll
    for (int i = 0; i < 4; ++i) {
        dh[i] = make_uint4(hw[4 * i], hw[4 * i + 1], hw[4 * i + 2], hw[4 * i + 3]);
        dl[i] = make_uint4(lw[4 * i], lw[4 * i + 1], lw[4 * i + 2], lw[4 * i + 3]);
    }
}

// ---------------- QKV GEMM: D[l][o] = xt[l][c] * W[o][c], hi/lo split ----------------
__global__ __launch_bounds__(256) void qkv_gemm(const unsigned short* __restrict__ xth,
                                                const unsigned short* __restrict__ xtl,
                                                const unsigned short* __restrict__ Wqh,
                                                const unsigned short* __restrict__ Wql,
                                                unsigned short* __restrict__ Qd,
                                                unsigned short* __restrict__ Kd,
                                                unsigned short* __restrict__ Vb) {
    int b = blockIdx.y;
    int wid = threadIdx.x >> 6, lane = threadIdx.x & 63, lm = lane & 15, lg = lane >> 4;
    int l0 = blockIdx.x * 64 + wid * 16;
    bf16x8 ah[4], al[4];
#pragma unroll
    for (int ks = 0; ks < 4; ++ks) {
        size_t off = ((size_t)b * LL + l0 + lm) * CCH + ks * 32 + 8 * lg;
        ah[ks] = *(const bf16x8*)(xth + off);
        al[ks] = *(const bf16x8*)(xtl + off);
    }
    f32x4 acc[24];
#pragma unroll
    for (int ot = 0; ot < 24; ++ot) acc[ot] = (f32x4){0.f, 0.f, 0.f, 0.f};
#pragma unroll
    for (int ot = 0; ot < 24; ++ot) {
#pragma unroll
        for (int ks = 0; ks < 4; ++ks) {
            size_t woff = (size_t)(ot * 16 + lm) * CCH + ks * 32 + 8 * lg;
            bf16x8 bh = *(const bf16x8*)(Wqh + woff);
            bf16x8 bl = *(const bf16x8*)(Wql + woff);
            acc[ot] = __builtin_amdgcn_mfma_f32_16x16x32_bf16(ah[ks], bh, acc[ot], 0, 0, 0);
            acc[ot] = __builtin_amdgcn_mfma_f32_16x16x32_bf16(ah[ks], bl, acc[ot], 0, 0, 0);
            acc[ot] = __builtin_amdgcn_mfma_f32_16x16x32_bf16(al[ks], bh, acc[ot], 0, 0, 0);
        }
    }
#pragma unroll
    for (int ot = 0; ot < 24; ++ot) {
        int t = ot >> 3, o_ = ot & 7;
        int h = o_ >> 1, d = (o_ & 1) * 16 + lm;
        unsigned short* base = (t == 0) ? Qd : (t == 1) ? Kd : Vb;
        uint2 u;
        u.x = cvtpk(acc[ot][0], acc[ot][1]);
        u.y = cvtpk(acc[ot][2], acc[ot][3]);
        *(uint2*)(base + ((size_t)(b * HEADS + h) * DH + d) * LL + l0 + 4 * lg) = u;
    }
}

// ---------------- transpose Qd/Kd[bh][d][l] -> Qb/Kb[bh][l][d] ----------------
__global__ __launch_bounds__(256) void trQK(const unsigned short* __restrict__ Qd,
                                            const unsigned short* __restrict__ Kd,
                                            unsigned short* __restrict__ Qb,
                                            unsigned short* __restrict__ Kb) {
    int lt = blockIdx.x, bh = blockIdx.y, sel = blockIdx.z;
    const unsigned short* src = sel ? Kd : Qd;
    unsigned short* dst = sel ? Kb : Qb;
    int l0 = lt * 256;
    __shared__ unsigned short st[32][264];
#pragma unroll
    for (int it = 0; it < 4; ++it) {
        int idx = it * 256 + threadIdx.x;  // over 1024 uint4 (8 bf16 each)
        int d = idx >> 5, l8 = idx & 31;
        uint4 v = *(const uint4*)(src + ((size_t)bh * DH + d) * LL + l0 + l8 * 8);
        *(uint4*)&st[d][l8 * 8] = v;
    }
    __syncthreads();
    int t = threadIdx.x;  // l = l0 + t
    unsigned w[16];
#pragma unroll
    for (int dp = 0; dp < 16; ++dp)
        w[dp] = (unsigned)st[2 * dp][t] | ((unsigned)st[2 * dp + 1][t] << 16);
    uint4* dp4 = (uint4*)(dst + ((size_t)bh * LL + l0 + t) * DH);
#pragma unroll
    for (int i = 0; i < 4; ++i)
        dp4[i] = make_uint4(w[4 * i], w[4 * i + 1], w[4 * i + 2], w[4 * i + 3]);
}

// ---------------- MFMA flash attention, fixed-max (bias in C-operand), split-KV x2 ----------------
__global__ __launch_bounds__(256) void attn_kernel(const unsigned short* __restrict__ Qb,
                                                   const unsigned short* __restrict__ Kb,
                                                   const unsigned short* __restrict__ Vb,
                                                   float* __restrict__ Acc, float* __restrict__ Ls) {
    __shared__ __align__(16) short Pl[4][16][72];
    int b = blockIdx.z, h = blockIdx.y, bh = b * HEADS + h;
    int sp = blockIdx.x & 1, qt = blockIdx.x >> 1;
    int wid = threadIdx.x >> 6, lane = threadIdx.x & 63, lm = lane & 15, lg = lane >> 4;
    int q0 = qt * 64 + wid * 16;
    int kv0 = sp * 2048;

    bf16x8 qf = *(const bf16x8*)(Qb + ((size_t)bh * LL + q0 + lm) * DH + 8 * lg);
    const unsigned short* Kbh = Kb + (size_t)bh * LL * DH;
    const unsigned short* Vbh = Vb + (size_t)bh * DH * LL;

    f32x4 accO[2] = {{0.f, 0.f, 0.f, 0.f}, {0.f, 0.f, 0.f, 0.f}};
    float plsum = 0.f;
    const f32x4 cbias = {-24.f, -24.f, -24.f, -24.f};  // fixed softmax max, log2 domain

    bf16x8 kf[4];
#pragma unroll
    for (int kc = 0; kc < 4; ++kc)
        kf[kc] = *(const bf16x8*)(Kbh + ((size_t)(kv0 + kc * 16 + lm)) * DH + 8 * lg);

    for (int m0 = kv0; m0 < kv0 + 2048; m0 += 64) {
        int mn = kv0 + ((m0 - kv0 + 64) & 2047);
        bf16x8 kn[4];
#pragma unroll
        for (int kc = 0; kc < 4; ++kc)
            kn[kc] = *(const bf16x8*)(Kbh + ((size_t)(mn + kc * 16 + lm)) * DH + 8 * lg);

        f32x4 s[4];
#pragma unroll
        for (int kc = 0; kc < 4; ++kc)
            s[kc] = __builtin_amdgcn_mfma_f32_16x16x32_bf16(kf[kc], qf, cbias, 0, 0, 0);

        bf16x8 vf[2][2];
#pragma unroll
        for (int ch = 0; ch < 2; ++ch)
#pragma unroll
            for (int dt = 0; dt < 2; ++dt)
                vf[ch][dt] = *(const bf16x8*)(Vbh + ((size_t)(dt * 16 + lm)) * LL + m0 + ch * 32 + 8 * lg);

#pragma unroll
        for (int kc = 0; kc < 4; ++kc) {
            float e0 = __builtin_amdgcn_exp2f(s[kc][0]);
            float e1 = __builtin_amdgcn_exp2f(s[kc][1]);
            float e2 = __builtin_amdgcn_exp2f(s[kc][2]);
            float e3 = __builtin_amdgcn_exp2f(s[kc][3]);
            plsum += (e0 + e1) + (e2 + e3);
            uint2 u;
            u.x = cvtpk(e0, e1);
            u.y = cvtpk(e2, e3);
            *(uint2*)&Pl[wid][lm][kc * 16 + 4 * lg] = u;
        }
        bf16x8 pf[2];
#pragma unroll
        for (int ch = 0; ch < 2; ++ch)
            pf[ch] = *(const bf16x8*)&Pl[wid][lm][ch * 32 + 8 * lg];

#pragma unroll
        for (int ch = 0; ch < 2; ++ch)
#pragma unroll
            for (int dt = 0; dt < 2; ++dt)
                accO[dt] = __builtin_amdgcn_mfma_f32_16x16x32_bf16(vf[ch][dt], pf[ch], accO[dt], 0, 0, 0);

#pragma unroll
        for (int kc = 0; kc < 4; ++kc) kf[kc] = kn[kc];
    }

    plsum += __shfl_xor(plsum, 16);
    plsum += __shfl_xor(plsum, 32);
#pragma unroll
    for (int dt = 0; dt < 2; ++dt)
        *(f32x4*)(Acc + ((size_t)(sp * 8 + bh) * LL + q0 + lm) * DH + dt * 16 + 4 * lg) = accO[dt];
    if (lg == 0) Ls[(size_t)sp * 8 * LL + (size_t)bh * LL + q0 + lm] = plsum;
}

// ---------------- combine splits -> Ot[b][l][c] bf16 ----------------
__global__ __launch_bounds__(256) void attn_combine(const float* __restrict__ Acc,
                                                    const float* __restrict__ Ls,
                                                    unsigned short* __restrict__ Ot) {
    int g = blockIdx.x * 256 + threadIdx.x;  // over 8*4096
    int bh = g >> 12, q = g & 4095;
    int b = bh >> 2, h = bh & 3;
    const f32x4* a0 = (const f32x4*)(Acc + ((size_t)bh * LL + q) * DH);
    const f32x4* a1 = (const f32x4*)(Acc + ((size_t)(8 + bh) * LL + q) * DH);
    float ls = Ls[(size_t)bh * LL + q] + Ls[(size_t)8 * LL + (size_t)bh * LL + q];
    float inv = 1.f / ls;
    unsigned ow[16];
#pragma unroll
    for (int i = 0; i < 8; ++i) {
        f32x4 v = a0[i] + a1[i];
        ow[2 * i] = cvtpk(v[0] * inv, v[1] * inv);
        ow[2 * i + 1] = cvtpk(v[2] * inv, v[3] * inv);
    }
    uint4* dst = (uint4*)(Ot + ((size_t)b * LL + q) * CCH + h * DH);
#pragma unroll
    for (int i = 0; i < 4; ++i)
        dst[i] = make_uint4(ow[4 * i], ow[4 * i + 1], ow[4 * i + 2], ow[4 * i + 3]);
}

// ---------------- out projection + bias + residual ----------------
__global__ __launch_bounds__(256) void out_gemm(const unsigned short* __restrict__ Ot,
                                                const unsigned short* __restrict__ Woh,
                                                const unsigned short* __restrict__ Wol,
                                                const float* __restrict__ bo,
                                                const float* __restrict__ x,
                                                float* __restrict__ out) {
    int b = blockIdx.y;
    int wid = threadIdx.x >> 6, lane = threadIdx.x & 63, lm = lane & 15, lg = lane >> 4;
    int l0 = blockIdx.x * 64 + wid * 16;
    bf16x8 af[4];
#pragma unroll
    for (int ks = 0; ks < 4; ++ks)
        af[ks] = *(const bf16x8*)(Ot + ((size_t)b * LL + l0 + lm) * CCH + ks * 32 + 8 * lg);
    f32x4 acc[8];
#pragma unroll
    for (int ot = 0; ot < 8; ++ot) acc[ot] = (f32x4){0.f, 0.f, 0.f, 0.f};
#pragma unroll
    for (int ot = 0; ot < 8; ++ot) {
#pragma unroll
        for (int ks = 0; ks < 4; ++ks) {
            size_t woff = (size_t)(ot * 16 + lm) * CCH + ks * 32 + 8 * lg;
            bf16x8 bh = *(const bf16x8*)(Woh + woff);
            bf16x8 bl = *(const bf16x8*)(Wol + woff);
            acc[ot] = __builtin_amdgcn_mfma_f32_16x16x32_bf16(af[ks], bh, acc[ot], 0, 0, 0);
            acc[ot] = __builtin_amdgcn_mfma_f32_16x16x32_bf16(af[ks], bl, acc[ot], 0, 0, 0);
        }
    }
#pragma unroll
    for (int ot = 0; ot < 8; ++ot) {
        int oc = ot * 16 + lm;
        float bias = bo[oc];
        size_t off = ((size_t)b * CCH + oc) * LL + l0 + 4 * lg;
        f32x4 xr = *(const f32x4*)(x + off);
        f32x4 r = acc[ot];
        r[0] += bias + xr[0];
        r[1] += bias + xr[1];
        r[2] += bias + xr[2];
        r[3] += bias + xr[3];
        *(f32x4*)(out + off) = r;
    }
}

extern "C" void kernel_launch(void* const* d_in, const int* in_sizes, int n_in,
                              void* d_out, int out_size, void* d_ws, size_t ws_size,
                              hipStream_t stream) {
    const float* x = (const float*)d_in[0];
    const float* gn_w = (const float*)d_in[1];
    const float* gn_b = (const float*)d_in[2];
    const float* w_qkv = (const float*)d_in[3];
    const float* w_out = (const float*)d_in[4];
    const float* b_out = (const float*)d_in[5];
    float* out = (float*)d_out;

    char* W = (char*)d_ws;
    unsigned short* xth = (unsigned short*)(W);              // [0,2M)
    unsigned short* xtl = (unsigned short*)(W + (2 << 20));  // [2,4M)
    unsigned short* Qd = (unsigned short*)(W + (4 << 20));   // [4,6M)
    unsigned short* Kd = (unsigned short*)(W + (6 << 20));   // [6,8M)
    unsigned short* Vb = (unsigned short*)(W + (8 << 20));   // [8,10M)
    unsigned short* Qb = (unsigned short*)(W + (10 << 20));  // [10,12M)
    unsigned short* Kb = (unsigned short*)(W + (12 << 20));  // [12,14M)
    float* Acc = (float*)(W);                                // [0,8M): reuses xth..Kd (dead by attn)
    float* Ls = (float*)(W + (14 << 20));                    // 256KB
    unsigned short* Ot = (unsigned short*)(W + (14 << 20) + (256 << 10));  // 2MB
    float* ps = (float*)(W + (17 << 20));
    float* ps2 = ps + 256;
    float* sm = ps2 + 256;
    float* sr = sm + 32;
    unsigned short* Wqh = (unsigned short*)(sr + 32);
    unsigned short* Wql = Wqh + 49152;
    unsigned short* Woh = Wql + 49152;
    unsigned short* Wol = Woh + 16384;

    gn_part<<<dim3(256), dim3(256), 0, stream>>>(x, ps, ps2);
    gn_final<<<dim3(1), dim3(64), 0, stream>>>(ps, ps2, sm, sr);
    prep_w<<<dim3(256), dim3(256), 0, stream>>>(w_qkv, w_out, Wqh, Wql, Woh, Wol);
    gn_apply_t<<<dim3(16, 4, BB), dim3(256), 0, stream>>>(x, gn_w, gn_b, sm, sr, xth, xtl);
    qkv_gemm<<<dim3(64, BB), dim3(256), 0, stream>>>(xth, xtl, Wqh, Wql, Qd, Kd, Vb);
    trQK<<<dim3(16, BB * HEADS, 2), dim3(256), 0, stream>>>(Qd, Kd, Qb, Kb);
    attn_kernel<<<dim3(128, HEADS, BB), dim3(256), 0, stream>>>(Qb, Kb, Vb, Acc, Ls);
    attn_combine<<<dim3(128), dim3(256), 0, stream>>>(Acc, Ls, Ot);
    out_gemm<<<dim3(64, BB), dim3(256), 0, stream>>>(Ot, Woh, Wol, b_out, x, out);
}

// Round 4
// 89.678 us; speedup vs baseline: 18.8253x; 1.8115x over previous
//
#include <hip/hip_runtime.h>
#include <math.h>

#define BB 2
#define CCH 128
#define LL 4096
#define HEADS 4
#define DH 32
#define EPSV 1e-5f

typedef float f32x4 __attribute__((ext_vector_type(4)));
typedef short bf16x8 __attribute__((ext_vector_type(8)));

__device__ inline unsigned short f2bf(float x) {
    union { float f; unsigned u; } v; v.f = x;
    unsigned r = v.u + 0x7fffu + ((v.u >> 16) & 1u);
    return (unsigned short)(r >> 16);
}
__device__ inline float bfbits2f(unsigned bits_hi16) {
    union { unsigned u; float f; } v; v.u = bits_hi16; return v.f;
}
__device__ inline unsigned cvtpk(float lo, float hi) {
    unsigned r;
    asm("v_cvt_pk_bf16_f32 %0, %1, %2" : "=v"(r) : "v"(lo), "v"(hi));
    return r;
}

// ---------------- GN pass 1: partial sums (one block per channel) ----------------
__global__ __launch_bounds__(256) void gn_part(const float* __restrict__ x,
                                               float* __restrict__ ps, float* __restrict__ ps2) {
    const float* xp = x + (size_t)blockIdx.x * 4096;
    float s = 0.f, s2 = 0.f;
#pragma unroll
    for (int it = 0; it < 4; ++it) {
        float4 v = *(const float4*)(xp + it * 1024 + threadIdx.x * 4);
        s += v.x + v.y + v.z + v.w;
        s2 += v.x * v.x + v.y * v.y + v.z * v.z + v.w * v.w;
    }
    for (int off = 32; off; off >>= 1) {
        s += __shfl_down(s, off);
        s2 += __shfl_down(s2, off);
    }
    __shared__ float rs[4], rs2[4];
    int wave = threadIdx.x >> 6, lane = threadIdx.x & 63;
    if (lane == 0) { rs[wave] = s; rs2[wave] = s2; }
    __syncthreads();
    if (threadIdx.x == 0) {
        ps[blockIdx.x] = rs[0] + rs[1] + rs[2] + rs[3];
        ps2[blockIdx.x] = rs2[0] + rs2[1] + rs2[2] + rs2[3];
    }
}

// ---------------- GN pass 2: finalize stats ----------------
__global__ void gn_final(const float* __restrict__ ps, const float* __restrict__ ps2,
                         float* __restrict__ sm, float* __restrict__ sr) {
    int t = threadIdx.x;
    if (t >= 32) return;
    float s = 0.f, s2 = 0.f;
#pragma unroll
    for (int i = 0; i < 8; ++i) { s += ps[t * 8 + i]; s2 += ps2[t * 8 + i]; }
    float mean = s / 32768.f;
    float var = s2 / 32768.f - mean * mean;
    sm[t] = mean;
    sr[t] = rsqrtf(var + EPSV);
}

// ---------------- W prep: hi/lo bf16 split; Q rows pre-scaled by log2e/sqrt(dh) ----------------
__global__ __launch_bounds__(256) void prep_w(const float* __restrict__ w_qkv,
                                              const float* __restrict__ w_out,
                                              unsigned short* __restrict__ Wqh, unsigned short* __restrict__ Wql,
                                              unsigned short* __restrict__ Woh, unsigned short* __restrict__ Wol) {
    int i = blockIdx.x * 256 + threadIdx.x;
    const float qscale = 0.2550350f;  // log2(e)/sqrt(32)
    if (i < 49152) {
        float v = w_qkv[i];
        if (i < 16384) v *= qscale;  // Q rows (o<128)
        unsigned short h = f2bf(v);
        Wqh[i] = h;
        Wql[i] = f2bf(v - bfbits2f((unsigned)h << 16));
    } else {
        int j = i - 49152;
        float v = w_out[j];
        unsigned short h = f2bf(v);
        Woh[j] = h;
        Wol[j] = f2bf(v - bfbits2f((unsigned)h << 16));
    }
}

// ---------------- GN apply + transpose: x[b][c][l] -> xth/xtl[b][l][c] bf16 ----------------
__global__ __launch_bounds__(256) void gn_apply_t(const float* __restrict__ x,
                                                  const float* __restrict__ gw, const float* __restrict__ gb,
                                                  const float* __restrict__ sm, const float* __restrict__ sr,
                                                  unsigned short* __restrict__ xth, unsigned short* __restrict__ xtl) {
    int lt = blockIdx.x, ct = blockIdx.y, b = blockIdx.z;
    int c0 = ct * 32, l0 = lt * 64;
    __shared__ float wsh[32], bsh[32], msh[4], rsh[4];
    __shared__ unsigned short sh[32][72], sl[32][72];
    if (threadIdx.x < 32) { wsh[threadIdx.x] = gw[c0 + threadIdx.x]; bsh[threadIdx.x] = gb[c0 + threadIdx.x]; }
    if (threadIdx.x < 4) {
        int g = (c0 >> 3) + threadIdx.x;
        msh[threadIdx.x] = sm[b * 16 + g];
        rsh[threadIdx.x] = sr[b * 16 + g];
    }
    __syncthreads();
#pragma unroll
    for (int it = 0; it < 2; ++it) {
        int idx = it * 256 + threadIdx.x;  // over 512 float4 (32c x 16 f4)
        int cc = idx >> 4, l4 = idx & 15;
        float4 v = *(const float4*)(x + ((size_t)(b * CCH + c0 + cc)) * LL + l0 + l4 * 4);
        float mn = msh[cc >> 3], rstd = rsh[cc >> 3], w = wsh[cc], bv = bsh[cc];
        float a0 = (v.x - mn) * rstd * w + bv;
        float a1 = (v.y - mn) * rstd * w + bv;
        float a2 = (v.z - mn) * rstd * w + bv;
        float a3 = (v.w - mn) * rstd * w + bv;
        unsigned uh01 = cvtpk(a0, a1), uh23 = cvtpk(a2, a3);
        float r0 = a0 - bfbits2f(uh01 << 16), r1 = a1 - bfbits2f(uh01 & 0xffff0000u);
        float r2 = a2 - bfbits2f(uh23 << 16), r3 = a3 - bfbits2f(uh23 & 0xffff0000u);
        unsigned ul01 = cvtpk(r0, r1), ul23 = cvtpk(r2, r3);
        *(uint2*)&sh[cc][l4 * 4] = make_uint2(uh01, uh23);
        *(uint2*)&sl[cc][l4 * 4] = make_uint2(ul01, ul23);
    }
    __syncthreads();
    int l = threadIdx.x >> 2, c8 = threadIdx.x & 3;  // l in [0,64), 8 channels per thread
    unsigned hw[4], lw[4];
#pragma unroll
    for (int j = 0; j < 4; ++j) {
        int c = c8 * 8 + 2 * j;
        hw[j] = (unsigned)sh[c][l] | ((unsigned)sh[c + 1][l] << 16);
        lw[j] = (unsigned)sl[c][l] | ((unsigned)sl[c + 1][l] << 16);
    }
    *(uint4*)(xth + ((size_t)b * LL + l0 + l) * CCH + c0 + c8 * 8) = make_uint4(hw[0], hw[1], hw[2], hw[3]);
    *(uint4*)(xtl + ((size_t)b * LL + l0 + l) * CCH + c0 + c8 * 8) = make_uint4(lw[0], lw[1], lw[2], lw[3]);
}

// ---------------- QKV GEMM: D[l][o] = xt[l][c] * W[o][c], hi/lo split; 1-wave blocks ----------------
__global__ __launch_bounds__(64) void qkv_gemm(const unsigned short* __restrict__ xth,
                                               const unsigned short* __restrict__ xtl,
                                               const unsigned short* __restrict__ Wqh,
                                               const unsigned short* __restrict__ Wql,
                                               unsigned short* __restrict__ Qd,
                                               unsigned short* __restrict__ Kd,
                                               unsigned short* __restrict__ Vb) {
    int lt = blockIdx.x, og = blockIdx.y, b = blockIdx.z;
    int lane = threadIdx.x & 63, lm = lane & 15, lg = lane >> 4;
    int l0 = lt * 16;
    bf16x8 ah[4], al[4];
#pragma unroll
    for (int ks = 0; ks < 4; ++ks) {
        size_t off = ((size_t)b * LL + l0 + lm) * CCH + ks * 32 + 8 * lg;
        ah[ks] = *(const bf16x8*)(xth + off);
        al[ks] = *(const bf16x8*)(xtl + off);
    }
    f32x4 acc[8];
#pragma unroll
    for (int ot = 0; ot < 8; ++ot) acc[ot] = (f32x4){0.f, 0.f, 0.f, 0.f};
#pragma unroll
    for (int ot = 0; ot < 8; ++ot) {
#pragma unroll
        for (int ks = 0; ks < 4; ++ks) {
            size_t woff = (size_t)((og * 8 + ot) * 16 + lm) * CCH + ks * 32 + 8 * lg;
            bf16x8 bh = *(const bf16x8*)(Wqh + woff);
            bf16x8 bl = *(const bf16x8*)(Wql + woff);
            acc[ot] = __builtin_amdgcn_mfma_f32_16x16x32_bf16(ah[ks], bh, acc[ot], 0, 0, 0);
            acc[ot] = __builtin_amdgcn_mfma_f32_16x16x32_bf16(ah[ks], bl, acc[ot], 0, 0, 0);
            acc[ot] = __builtin_amdgcn_mfma_f32_16x16x32_bf16(al[ks], bh, acc[ot], 0, 0, 0);
        }
    }
    unsigned short* base = (og == 0) ? Qd : (og == 1) ? Kd : Vb;
#pragma unroll
    for (int ot = 0; ot < 8; ++ot) {
        int h = ot >> 1, d = (ot & 1) * 16 + lm;
        uint2 u;
        u.x = cvtpk(acc[ot][0], acc[ot][1]);
        u.y = cvtpk(acc[ot][2], acc[ot][3]);
        *(uint2*)(base + ((size_t)(b * HEADS + h) * DH + d) * LL + l0 + 4 * lg) = u;
    }
}

// ---------------- transpose Qd/Kd[bh][d][l] -> Qb/Kb[bh][l][d] ----------------
__global__ __launch_bounds__(256) void trQK(const unsigned short* __restrict__ Qd,
                                            const unsigned short* __restrict__ Kd,
                                            unsigned short* __restrict__ Qb,
                                            unsigned short* __restrict__ Kb) {
    int lt = blockIdx.x, bh = blockIdx.y, sel = blockIdx.z;
    const unsigned short* src = sel ? Kd : Qd;
    unsigned short* dst = sel ? Kb : Qb;
    int l0 = lt * 256;
    __shared__ unsigned short st[32][264];
#pragma unroll
    for (int it = 0; it < 4; ++it) {
        int idx = it * 256 + threadIdx.x;  // over 1024 uint4 (8 bf16 each)
        int d = idx >> 5, l8 = idx & 31;
        uint4 v = *(const uint4*)(src + ((size_t)bh * DH + d) * LL + l0 + l8 * 8);
        *(uint4*)&st[d][l8 * 8] = v;
    }
    __syncthreads();
    int t = threadIdx.x;  // l = l0 + t
    unsigned w[16];
#pragma unroll
    for (int dp = 0; dp < 16; ++dp)
        w[dp] = (unsigned)st[2 * dp][t] | ((unsigned)st[2 * dp + 1][t] << 16);
    uint4* dp4 = (uint4*)(dst + ((size_t)bh * LL + l0 + t) * DH);
#pragma unroll
    for (int i = 0; i < 4; ++i)
        dp4[i] = make_uint4(w[4 * i], w[4 * i + 1], w[4 * i + 2], w[4 * i + 3]);
}

// ---------------- MFMA flash attention: LDS-staged K/V shared by 4 waves, 128q/block ----------------
// grid.x = 512 linear: id = qb*16 + (bh*2+sp)  =>  id%8 pins each (bh,sp) to one XCD
__global__ __launch_bounds__(256) void attn_kernel(const unsigned short* __restrict__ Qp,
                                                   const unsigned short* __restrict__ Kp,
                                                   const unsigned short* __restrict__ Vp,
                                                   float* __restrict__ Acc, float* __restrict__ Ls) {
    __shared__ __align__(16) unsigned short Ksh[64][40];   // 80B rows: 16B-aligned, 2-way banks
    __shared__ __align__(16) unsigned short Vsh[32][72];   // 144B rows
    __shared__ __align__(16) short Pl[4][2][16][72];
    int id = blockIdx.x;
    int combo = id & 15, qb = id >> 4;
    int bh = combo >> 1, sp = combo & 1;
    int wid = threadIdx.x >> 6, lane = threadIdx.x & 63, lm = lane & 15, lg = lane >> 4;
    int q0 = qb * 128 + wid * 32;
    int kv0 = sp * 2048;
    int t = threadIdx.x;

    const unsigned short* Kbh = Kp + (size_t)bh * LL * DH;
    const unsigned short* Vbh = Vp + (size_t)bh * DH * LL;

    bf16x8 qf[2];
    qf[0] = *(const bf16x8*)(Qp + ((size_t)bh * LL + q0 + lm) * DH + 8 * lg);
    qf[1] = *(const bf16x8*)(Qp + ((size_t)bh * LL + q0 + 16 + lm) * DH + 8 * lg);

    f32x4 accO[2][2];
#pragma unroll
    for (int qi = 0; qi < 2; ++qi)
#pragma unroll
        for (int dt = 0; dt < 2; ++dt) accO[qi][dt] = (f32x4){0.f, 0.f, 0.f, 0.f};
    float plsum[2] = {0.f, 0.f};
    const f32x4 cbias = {-24.f, -24.f, -24.f, -24.f};  // fixed softmax max, log2 domain

    // staging: each thread owns one 16B chunk of K tile and one of V tile
    int skv = t >> 2, ssl = (t & 3) * 8;   // K[64 kv][32 d]
    int svd = t >> 3, svs = (t & 7) * 8;   // V[32 d][64 kv]
    const uint4* gK = (const uint4*)(Kbh + (size_t)(kv0 + skv) * DH + ssl);
    const uint4* gV = (const uint4*)(Vbh + (size_t)svd * LL + kv0 + svs);
    uint4 kreg = *gK; gK += 256;   // 64*32 shorts / 8 per uint4
    uint4 vreg = *gV; gV += 8;     // 64 shorts / 8

    for (int tt = 0; tt < 32; ++tt) {
        __syncthreads();                      // all waves done reading previous tile
        *(uint4*)&Ksh[skv][ssl] = kreg;       // (compiler waits vmcnt for kreg/vreg)
        *(uint4*)&Vsh[svd][svs] = vreg;
        __syncthreads();
        if (tt < 31) { kreg = *gK; gK += 256; vreg = *gV; gV += 8; }  // prefetch next tile

        bf16x8 kf[4];
#pragma unroll
        for (int kc = 0; kc < 4; ++kc)
            kf[kc] = *(const bf16x8*)&Ksh[kc * 16 + lm][lg * 8];
        f32x4 s[2][4];
#pragma unroll
        for (int qi = 0; qi < 2; ++qi)
#pragma unroll
            for (int kc = 0; kc < 4; ++kc)
                s[qi][kc] = __builtin_amdgcn_mfma_f32_16x16x32_bf16(kf[kc], qf[qi], cbias, 0, 0, 0);

        bf16x8 vf[2][2];
#pragma unroll
        for (int ch = 0; ch < 2; ++ch)
#pragma unroll
            for (int dt = 0; dt < 2; ++dt)
                vf[ch][dt] = *(const bf16x8*)&Vsh[dt * 16 + lm][ch * 32 + 8 * lg];

#pragma unroll
        for (int qi = 0; qi < 2; ++qi) {
#pragma unroll
            for (int kc = 0; kc < 4; ++kc) {
                float e0 = __builtin_amdgcn_exp2f(s[qi][kc][0]);
                float e1 = __builtin_amdgcn_exp2f(s[qi][kc][1]);
                float e2 = __builtin_amdgcn_exp2f(s[qi][kc][2]);
                float e3 = __builtin_amdgcn_exp2f(s[qi][kc][3]);
                plsum[qi] += (e0 + e1) + (e2 + e3);
                uint2 u;
                u.x = cvtpk(e0, e1);
                u.y = cvtpk(e2, e3);
                *(uint2*)&Pl[wid][qi][lm][kc * 16 + 4 * lg] = u;
            }
            bf16x8 pf[2];
#pragma unroll
            for (int ch = 0; ch < 2; ++ch)
                pf[ch] = *(const bf16x8*)&Pl[wid][qi][lm][ch * 32 + 8 * lg];
#pragma unroll
            for (int ch = 0; ch < 2; ++ch)
#pragma unroll
                for (int dt = 0; dt < 2; ++dt)
                    accO[qi][dt] = __builtin_amdgcn_mfma_f32_16x16x32_bf16(vf[ch][dt], pf[ch], accO[qi][dt], 0, 0, 0);
        }
    }

#pragma unroll
    for (int qi = 0; qi < 2; ++qi) {
        float pl = plsum[qi];
        pl += __shfl_xor(pl, 16);
        pl += __shfl_xor(pl, 32);
#pragma unroll
        for (int dt = 0; dt < 2; ++dt)
            *(f32x4*)(Acc + ((size_t)(sp * 8 + bh) * LL + q0 + qi * 16 + lm) * DH + dt * 16 + 4 * lg) = accO[qi][dt];
        if (lg == 0) Ls[(size_t)(sp * 8 + bh) * LL + q0 + qi * 16 + lm] = pl;
    }
}

// ---------------- out projection + split-combine + bias + residual ----------------
// block: 4 waves, all same 16 l; wave wid owns output channels [wid*32, wid*32+32)
__global__ __launch_bounds__(256) void out_gemm(const float* __restrict__ Acc,
                                                const float* __restrict__ Ls,
                                                const unsigned short* __restrict__ Woh,
                                                const unsigned short* __restrict__ Wol,
                                                const float* __restrict__ bo,
                                                const float* __restrict__ x,
                                                float* __restrict__ out) {
    int lt = blockIdx.x, b = blockIdx.y;
    int wid = threadIdx.x >> 6, lane = threadIdx.x & 63, lm = lane & 15, lg = lane >> 4;
    int l0 = lt * 16;
    // combine splits inline: af[ks] = O[head ks][l0+lm][8lg..8lg+7] in bf16
    bf16x8 af[4];
#pragma unroll
    for (int ks = 0; ks < 4; ++ks) {
        int bh = b * HEADS + ks;
        size_t base0 = ((size_t)bh * LL + l0 + lm) * DH + 8 * lg;
        size_t base1 = ((size_t)(8 + bh) * LL + l0 + lm) * DH + 8 * lg;
        f32x4 a0 = *(const f32x4*)(Acc + base0);
        f32x4 a0b = *(const f32x4*)(Acc + base0 + 4);
        f32x4 a1 = *(const f32x4*)(Acc + base1);
        f32x4 a1b = *(const f32x4*)(Acc + base1 + 4);
        float ls = Ls[(size_t)bh * LL + l0 + lm] + Ls[(size_t)(8 + bh) * LL + l0 + lm];
        float inv = 1.f / ls;
        f32x4 o0 = (a0 + a1), o1 = (a0b + a1b);
        union { unsigned u[4]; bf16x8 v; } cv;
        cv.u[0] = cvtpk(o0[0] * inv, o0[1] * inv);
        cv.u[1] = cvtpk(o0[2] * inv, o0[3] * inv);
        cv.u[2] = cvtpk(o1[0] * inv, o1[1] * inv);
        cv.u[3] = cvtpk(o1[2] * inv, o1[3] * inv);
        af[ks] = cv.v;
    }
    f32x4 acc[2];
    acc[0] = (f32x4){0.f, 0.f, 0.f, 0.f};
    acc[1] = (f32x4){0.f, 0.f, 0.f, 0.f};
#pragma unroll
    for (int oi = 0; oi < 2; ++oi) {
        int ot = wid * 2 + oi;
#pragma unroll
        for (int ks = 0; ks < 4; ++ks) {
            size_t woff = (size_t)(ot * 16 + lm) * CCH + ks * 32 + 8 * lg;
            bf16x8 bh = *(const bf16x8*)(Woh + woff);
            bf16x8 bl = *(const bf16x8*)(Wol + woff);
            acc[oi] = __builtin_amdgcn_mfma_f32_16x16x32_bf16(af[ks], bh, acc[oi], 0, 0, 0);
            acc[oi] = __builtin_amdgcn_mfma_f32_16x16x32_bf16(af[ks], bl, acc[oi], 0, 0, 0);
        }
    }
#pragma unroll
    for (int oi = 0; oi < 2; ++oi) {
        int oc = (wid * 2 + oi) * 16 + lm;
        float bias = bo[oc];
        size_t off = ((size_t)b * CCH + oc) * LL + l0 + 4 * lg;
        f32x4 xr = *(const f32x4*)(x + off);
        f32x4 r = acc[oi];
        r[0] += bias + xr[0];
        r[1] += bias + xr[1];
        r[2] += bias + xr[2];
        r[3] += bias + xr[3];
        *(f32x4*)(out + off) = r;
    }
}

extern "C" void kernel_launch(void* const* d_in, const int* in_sizes, int n_in,
                              void* d_out, int out_size, void* d_ws, size_t ws_size,
                              hipStream_t stream) {
    const float* x = (const float*)d_in[0];
    const float* gn_w = (const float*)d_in[1];
    const float* gn_b = (const float*)d_in[2];
    const float* w_qkv = (const float*)d_in[3];
    const float* w_out = (const float*)d_in[4];
    const float* b_out = (const float*)d_in[5];
    float* out = (float*)d_out;

    char* W = (char*)d_ws;
    unsigned short* xth = (unsigned short*)(W);              // [0,2M)
    unsigned short* xtl = (unsigned short*)(W + (2 << 20));  // [2,4M)
    unsigned short* Qd = (unsigned short*)(W + (4 << 20));   // [4,6M)
    unsigned short* Kd = (unsigned short*)(W + (6 << 20));   // [6,8M)
    unsigned short* Vb = (unsigned short*)(W + (8 << 20));   // [8,10M)
    unsigned short* Qb = (unsigned short*)(W + (10 << 20));  // [10,12M)
    unsigned short* Kb = (unsigned short*)(W + (12 << 20));  // [12,14M)
    float* Acc = (float*)(W);                                // [0,8M): reuses xth..Kd (dead by attn)
    float* Ls = (float*)(W + (14 << 20));                    // 256KB
    float* ps = (float*)(W + (15 << 20));
    float* ps2 = ps + 256;
    float* sm = ps2 + 256;
    float* sr = sm + 32;
    unsigned short* Wqh = (unsigned short*)(sr + 32);
    unsigned short* Wql = Wqh + 49152;
    unsigned short* Woh = Wql + 49152;
    unsigned short* Wol = Woh + 16384;

    gn_part<<<dim3(256), dim3(256), 0, stream>>>(x, ps, ps2);
    gn_final<<<dim3(1), dim3(64), 0, stream>>>(ps, ps2, sm, sr);
    prep_w<<<dim3(256), dim3(256), 0, stream>>>(w_qkv, w_out, Wqh, Wql, Woh, Wol);
    gn_apply_t<<<dim3(64, 4, BB), dim3(256), 0, stream>>>(x, gn_w, gn_b, sm, sr, xth, xtl);
    qkv_gemm<<<dim3(256, 3, BB), dim3(64), 0, stream>>>(xth, xtl, Wqh, Wql, Qd, Kd, Vb);
    trQK<<<dim3(16, BB * HEADS, 2), dim3(256), 0, stream>>>(Qd, Kd, Qb, Kb);
    attn_kernel<<<dim3(512), dim3(256), 0, stream>>>(Qb, Kb, Vb, Acc, Ls);
    out_gemm<<<dim3(256, BB), dim3(256), 0, stream>>>(Acc, Ls, Woh, Wol, b_out, x, out);
}